// Round 1
// baseline (807.753 us; speedup 1.0000x reference)
//
#include <hip/hip_runtime.h>
#include <hip/hip_bf16.h>

#define N_NODESC 50000
#define N_EDGESC 1600000
#define NGC 1024
#define NPC 8

// ---------------- qa effective weights: fold h3=[b,e,b+e,b+2e] into qa_w ----
__global__ void qaeff_kernel(const float* __restrict__ qaw, float* __restrict__ eff) {
  int k = blockIdx.x;           // output row 0..255
  int j = threadIdx.x;          // 0..127
  const float* r = qaw + (size_t)k * 256;
  float v;
  if (j < 64) {
    v = r[j] + r[128 + j] + r[192 + j];
  } else {
    int j2 = j - 64;
    v = r[64 + j2] + r[128 + j2] + 2.0f * r[192 + j2];
  }
  eff[(size_t)k * 128 + j] = v;
}

// ---------------- CSR build (by dst) ----------------
__global__ void count_kernel(const int* __restrict__ dst, int* __restrict__ cnt, int E) {
  int e = blockIdx.x * blockDim.x + threadIdx.x;
  if (e < E) atomicAdd(&cnt[dst[e]], 1);
}

__global__ __launch_bounds__(1024) void scan_kernel(const int* __restrict__ cnt,
                                                    int* __restrict__ rp, int N) {
  __shared__ int sdata[1024];
  __shared__ int carry;
  int tid = threadIdx.x;
  if (tid == 0) { carry = 0; rp[0] = 0; }
  __syncthreads();
  for (int base = 0; base < N; base += 1024) {
    int i = base + tid;
    int v = (i < N) ? cnt[i] : 0;
    sdata[tid] = v;
    __syncthreads();
    for (int off = 1; off < 1024; off <<= 1) {
      int t = (tid >= off) ? sdata[tid - off] : 0;
      __syncthreads();
      sdata[tid] += t;
      __syncthreads();
    }
    int inc = sdata[tid] + carry;
    if (i < N) rp[i + 1] = inc;
    __syncthreads();
    if (tid == 1023) carry = inc;
    __syncthreads();
  }
}

__global__ void fill_kernel(const int* __restrict__ src, const int* __restrict__ dst,
                            const int* __restrict__ rp, int* __restrict__ cur,
                            int* __restrict__ elist, int E) {
  int e = blockIdx.x * blockDim.x + threadIdx.x;
  if (e < E) {
    int d = dst[e];
    int pos = atomicAdd(&cur[d], 1);
    elist[rp[d] + pos] = src[e];
  }
}

// ---------------- generic fp32 tiled GEMM: C = act(A @ W^T + b) -------------
// MODE_A==1: A is built on the fly from x/emb24/emb72 (the 68-dim embedding).
// Only needs K<=any, Co a multiple of 64.
#define BM 64
#define BN 64
#define BKT 16

template <int MODE_A>
__global__ __launch_bounds__(256) void gemm_kernel(
    const float* __restrict__ A, int lda, const int* __restrict__ x,
    const float* __restrict__ e24, const float* __restrict__ e72,
    const float* __restrict__ W, int ldw, const float* __restrict__ bias,
    float* __restrict__ C, int ldc, int M, int K, int relu) {
  __shared__ float As[BKT][BM + 4];
  __shared__ float Bs[BKT][BN + 4];
  int tid = threadIdx.x;
  int row0 = blockIdx.x * BM;
  int col0 = blockIdx.y * BN;
  int tx = tid & 15, ty = tid >> 4;
  float acc[4][4] = {};
  for (int k0 = 0; k0 < K; k0 += BKT) {
#pragma unroll
    for (int r = 0; r < 4; ++r) {
      int m = (tid >> 4) + r * 16;
      int k = tid & 15;
      int gi = row0 + m, gk = k0 + k;
      float v = 0.f;
      if (gi < M && gk < K) {
        if (MODE_A == 0) {
          v = A[(size_t)gi * lda + gk];
        } else {
          if (gk < 4) v = (float)x[gi * 4 + gk];
          else if (gk < 36) { int kk = gk - 4;  int f = kk >> 3, c = kk & 7; v = e24[(x[gi * 4 + f] % 24) * 8 + c]; }
          else             { int kk = gk - 36; int f = kk >> 3, c = kk & 7; v = e72[(x[gi * 4 + f] % 72) * 8 + c]; }
        }
      }
      As[k][m] = v;
    }
#pragma unroll
    for (int r = 0; r < 4; ++r) {
      int n = (tid >> 4) + r * 16;
      int k = tid & 15;
      int gk = k0 + k;
      float v = 0.f;
      if (gk < K) v = W[(size_t)(col0 + n) * ldw + gk];
      Bs[k][n] = v;
    }
    __syncthreads();
#pragma unroll
    for (int k = 0; k < BKT; ++k) {
      float a[4], b[4];
#pragma unroll
      for (int r = 0; r < 4; ++r) a[r] = As[k][ty * 4 + r];
#pragma unroll
      for (int c = 0; c < 4; ++c) b[c] = Bs[k][tx * 4 + c];
#pragma unroll
      for (int r = 0; r < 4; ++r)
#pragma unroll
        for (int c = 0; c < 4; ++c) acc[r][c] += a[r] * b[c];
    }
    __syncthreads();
  }
#pragma unroll
  for (int r = 0; r < 4; ++r) {
    int gi = row0 + ty * 4 + r;
    if (gi >= M) continue;
#pragma unroll
    for (int c = 0; c < 4; ++c) {
      int gj = col0 + tx * 4 + c;
      float v = acc[r][c] + bias[gj];
      if (relu) v = fmaxf(v, 0.f);
      C[(size_t)gi * ldc + gj] = v;
    }
  }
}

// ---------------- aggregation: h2[n] = 2*linx[n] + sum_{e->n} linx[src] -----
__global__ __launch_bounds__(128) void aggregate_kernel(const float* __restrict__ linx,
                                                        const int* __restrict__ rp,
                                                        const int* __restrict__ elist,
                                                        float* __restrict__ h2) {
  int n = blockIdx.x;
  int j = threadIdx.x;  // 0..127
  int beg = rp[n], end = rp[n + 1];
  float acc = 2.0f * linx[(size_t)n * 128 + j];
  for (int e = beg; e < end; ++e) {
    int s = elist[e];
    acc += linx[(size_t)s * 128 + j];
  }
  h2[(size_t)n * 128 + j] = acc;
}

// ---------------- global mean pool (batch is sorted) ------------------------
__global__ __launch_bounds__(256) void pool_kernel(const float* __restrict__ h,
                                                   const int* __restrict__ batch,
                                                   float* __restrict__ g) {
  int gg = blockIdx.x;   // graph id
  int j = threadIdx.x;   // 0..255
  int lo = 0, hi = N_NODESC;
  while (lo < hi) { int mid = (lo + hi) >> 1; if (batch[mid] < gg) lo = mid + 1; else hi = mid; }
  int beg = lo;
  hi = N_NODESC;
  while (lo < hi) { int mid = (lo + hi) >> 1; if (batch[mid] < gg + 1) lo = mid + 1; else hi = mid; }
  int end = lo;
  float acc = 0.f;
  for (int n = beg; n < end; ++n) acc += h[(size_t)n * 256 + j];
  float c = (float)(end - beg);
  g[(size_t)gg * 256 + j] = acc / fmaxf(c, 1.0f);
}

// ---------------- per-property heads (8 graphs per block) -------------------
__global__ __launch_bounds__(128) void head_kernel(const float* __restrict__ g,
    const float* __restrict__ w1, const float* __restrict__ b1,
    const float* __restrict__ w2, const float* __restrict__ b2,
    float* __restrict__ out) {
  int p = blockIdx.y;
  int g0 = blockIdx.x * 8;
  int t = threadIdx.x;  // 0..127  (= hidden unit h')
  __shared__ float gs[8][256];
  for (int i = t; i < 8 * 256; i += 128)
    gs[i >> 8][i & 255] = g[(size_t)(g0 + (i >> 8)) * 256 + (i & 255)];
  __syncthreads();
  const float4* w4 = (const float4*)(w1 + ((size_t)p * 128 + t) * 256);
  float bv = b1[p * 128 + t];
  float acc[8];
#pragma unroll
  for (int q = 0; q < 8; ++q) acc[q] = bv;
  for (int d4 = 0; d4 < 64; ++d4) {
    float4 wv = w4[d4];
#pragma unroll
    for (int q = 0; q < 8; ++q) {
      acc[q] += gs[q][d4 * 4 + 0] * wv.x + gs[q][d4 * 4 + 1] * wv.y +
                gs[q][d4 * 4 + 2] * wv.z + gs[q][d4 * 4 + 3] * wv.w;
    }
  }
  float w2v = w2[p * 128 + t];
  __shared__ float red[2][8];
  int wave = t >> 6, lane = t & 63;
#pragma unroll
  for (int q = 0; q < 8; ++q) {
    float v = fmaxf(acc[q], 0.f) * w2v;
    for (int o = 32; o > 0; o >>= 1) v += __shfl_down(v, o, 64);
    if (lane == 0) red[wave][q] = v;
  }
  __syncthreads();
  if (t < 8) out[(size_t)(g0 + t) * 8 + p] = red[0][t] + red[1][t] + b2[p];
}

extern "C" void kernel_launch(void* const* d_in, const int* in_sizes, int n_in,
                              void* d_out, int out_size, void* d_ws, size_t ws_size,
                              hipStream_t stream) {
  const int*   x     = (const int*)d_in[0];
  const int*   ei    = (const int*)d_in[1];
  const int*   batch = (const int*)d_in[2];
  const float* emb24 = (const float*)d_in[3];
  const float* emb72 = (const float*)d_in[4];
  const float* lin1w = (const float*)d_in[5];
  const float* lin1b = (const float*)d_in[6];
  const float* qa1w  = (const float*)d_in[7];
  const float* qa1b  = (const float*)d_in[8];
  const float* lin2w = (const float*)d_in[9];
  const float* lin2b = (const float*)d_in[10];
  const float* qa2w  = (const float*)d_in[11];
  const float* qa2b  = (const float*)d_in[12];
  const float* hw1   = (const float*)d_in[13];
  const float* hb1   = (const float*)d_in[14];
  const float* hw2   = (const float*)d_in[15];
  const float* hb2   = (const float*)d_in[16];
  float* out = (float*)d_out;

  const int* srcv = ei;
  const int* dstv = ei + N_EDGESC;

  char* wsb = (char*)d_ws;
  size_t off = 0;
  auto alloc = [&](size_t b) { char* p = wsb + off; off += (b + 255) & ~(size_t)255; return p; };
  float* linx  = (float*)alloc((size_t)N_NODESC * 128 * 4);
  float* h2    = (float*)alloc((size_t)N_NODESC * 128 * 4);
  float* h     = (float*)alloc((size_t)N_NODESC * 256 * 4);
  float* gbuf  = (float*)alloc((size_t)NGC * 256 * 4);
  float* qe1   = (float*)alloc(256 * 128 * 4);
  float* qe2   = (float*)alloc(256 * 128 * 4);
  int*   rp    = (int*)alloc((size_t)(N_NODESC + 1) * 4);
  int*   cnt   = (int*)alloc((size_t)N_NODESC * 4);
  int*   elist = (int*)alloc((size_t)N_EDGESC * 4);

  // CSR build (reused by both layers)
  hipMemsetAsync(cnt, 0, (size_t)N_NODESC * 4, stream);
  count_kernel<<<(N_EDGESC + 255) / 256, 256, 0, stream>>>(dstv, cnt, N_EDGESC);
  scan_kernel<<<1, 1024, 0, stream>>>(cnt, rp, N_NODESC);
  hipMemsetAsync(cnt, 0, (size_t)N_NODESC * 4, stream);
  fill_kernel<<<(N_EDGESC + 255) / 256, 256, 0, stream>>>(srcv, dstv, rp, cnt, elist, N_EDGESC);

  qaeff_kernel<<<256, 128, 0, stream>>>(qa1w, qe1);
  qaeff_kernel<<<256, 128, 0, stream>>>(qa2w, qe2);

  dim3 blk(256);
  int gm = (N_NODESC + BM - 1) / BM;

  // layer 1
  gemm_kernel<1><<<dim3(gm, 2), blk, 0, stream>>>(nullptr, 0, x, emb24, emb72,
      lin1w, 68, lin1b, linx, 128, N_NODESC, 68, 0);
  aggregate_kernel<<<N_NODESC, 128, 0, stream>>>(linx, rp, elist, h2);
  gemm_kernel<0><<<dim3(gm, 4), blk, 0, stream>>>(h2, 128, nullptr, nullptr, nullptr,
      qe1, 128, qa1b, h, 256, N_NODESC, 128, 1);

  // layer 2
  gemm_kernel<0><<<dim3(gm, 2), blk, 0, stream>>>(h, 256, nullptr, nullptr, nullptr,
      lin2w, 256, lin2b, linx, 128, N_NODESC, 256, 0);
  aggregate_kernel<<<N_NODESC, 128, 0, stream>>>(linx, rp, elist, h2);
  gemm_kernel<0><<<dim3(gm, 4), blk, 0, stream>>>(h2, 128, nullptr, nullptr, nullptr,
      qe2, 128, qa2b, h, 256, N_NODESC, 128, 1);

  // pool + heads
  pool_kernel<<<NGC, 256, 0, stream>>>(h, batch, gbuf);
  head_kernel<<<dim3(NGC / 8, NPC), 128, 0, stream>>>(gbuf, hw1, hb1, hw2, hb2, out);
}

// Round 2
// 550.578 us; speedup vs baseline: 1.4671x; 1.4671x over previous
//
#include <hip/hip_runtime.h>
#include <hip/hip_bf16.h>

#define N_NODESC 50000
#define N_EDGESC 1600000
#define NGC 1024
#define NPC 8

typedef __attribute__((ext_vector_type(8))) short bf16x8;
typedef __attribute__((ext_vector_type(4))) float f32x4;

__device__ inline ushort f2bf(float f) {
  union { float f; uint u; } v; v.f = f;
  uint u = v.u;
  u += 0x7FFF + ((u >> 16) & 1);
  return (ushort)(u >> 16);
}
__device__ inline float bflo(uint u) {
  union { uint u; float f; } v; v.u = u << 16; return v.f;
}
__device__ inline float bfhi(uint u) {
  union { uint u; float f; } v; v.u = u & 0xFFFF0000u; return v.f;
}

// ---------------- weight prep ----------------
// qa fold: h3=[b,e,b+e,b+2e] into qa_w -> eff [256][128] bf16
__global__ void prep_qaeff(const float* __restrict__ qaw, ushort* __restrict__ eff) {
  int k = blockIdx.x;           // output row 0..255
  int j = threadIdx.x;          // 0..127
  const float* r = qaw + (size_t)k * 256;
  float v;
  if (j < 64) {
    v = r[j] + r[128 + j] + r[192 + j];
  } else {
    int j2 = j - 64;
    v = r[64 + j2] + r[128 + j2] + 2.0f * r[192 + j2];
  }
  eff[(size_t)k * 128 + j] = f2bf(v);
}

// lin1 rows 0..127, K padded 68 -> 96
__global__ void prep_lin1(const float* __restrict__ w, ushort* __restrict__ o) {
  int r = blockIdx.x;           // 0..127
  int t = threadIdx.x;          // 0..127 (guard 96)
  if (t < 96) o[(size_t)r * 96 + t] = (t < 68) ? f2bf(w[(size_t)r * 68 + t]) : (ushort)0;
}

// lin2 rows 0..127 of [256,256]
__global__ void prep_lin2(const float* __restrict__ w, ushort* __restrict__ o) {
  int r = blockIdx.x;           // 0..127
  int t = threadIdx.x;          // 0..255
  o[(size_t)r * 256 + t] = f2bf(w[(size_t)r * 256 + t]);
}

// node features: [N,96] bf16 (cols 68..95 zero)
__global__ void feat_kernel(const int* __restrict__ x, const float* __restrict__ e24,
                            const float* __restrict__ e72, ushort* __restrict__ feat) {
  int n = blockIdx.x;
  int t = threadIdx.x;          // 0..127
  if (t >= 96) return;
  float v = 0.f;
  if (t < 4) v = (float)x[n * 4 + t];
  else if (t < 36) { int kk = t - 4;  int f = kk >> 3, c = kk & 7; v = e24[(x[n * 4 + f] % 24) * 8 + c]; }
  else if (t < 68) { int kk = t - 36; int f = kk >> 3, c = kk & 7; v = e72[(x[n * 4 + f] % 72) * 8 + c]; }
  feat[(size_t)n * 96 + t] = f2bf(v);
}

// ---------------- CSR build (by dst) ----------------
__global__ void count_kernel(const int* __restrict__ dst, int* __restrict__ cnt, int E) {
  int e = blockIdx.x * blockDim.x + threadIdx.x;
  if (e < E) atomicAdd(&cnt[dst[e]], 1);
}

__global__ __launch_bounds__(1024) void scan_kernel(const int* __restrict__ cnt,
                                                    int* __restrict__ rp, int N) {
  __shared__ int sdata[1024];
  __shared__ int carry;
  int tid = threadIdx.x;
  if (tid == 0) { carry = 0; rp[0] = 0; }
  __syncthreads();
  for (int base = 0; base < N; base += 1024) {
    int i = base + tid;
    int v = (i < N) ? cnt[i] : 0;
    sdata[tid] = v;
    __syncthreads();
    for (int off = 1; off < 1024; off <<= 1) {
      int t = (tid >= off) ? sdata[tid - off] : 0;
      __syncthreads();
      sdata[tid] += t;
      __syncthreads();
    }
    int inc = sdata[tid] + carry;
    if (i < N) rp[i + 1] = inc;
    __syncthreads();
    if (tid == 1023) carry = inc;
    __syncthreads();
  }
}

__global__ void fill_kernel(const int* __restrict__ src, const int* __restrict__ dst,
                            const int* __restrict__ rp, int* __restrict__ cur,
                            int* __restrict__ elist, int E) {
  int e = blockIdx.x * blockDim.x + threadIdx.x;
  if (e < E) {
    int d = dst[e];
    int pos = atomicAdd(&cur[d], 1);
    elist[rp[d] + pos] = src[e];
  }
}

// ---------------- MFMA GEMM: C[M,NC] = act(A[M,K] @ W[NC,K]^T + b) ----------
// grid.x = ceil(M/128), grid.y = NC/128; 256 threads = 4 waves, each wave 32 rows.
__global__ __launch_bounds__(256) void mfma_gemm(
    const ushort* __restrict__ A, const ushort* __restrict__ W,
    const float* __restrict__ bias, ushort* __restrict__ C,
    int M, int K, int NC, int relu) {
  int lane = threadIdx.x & 63;
  int wv = threadIdx.x >> 6;
  int rbase = blockIdx.x * 128 + wv * 32;
  int colt = blockIdx.y * 128;
  int r16 = lane & 15;
  int kg = (lane >> 4) * 8;

  f32x4 acc[2][8];
#pragma unroll
  for (int m = 0; m < 2; ++m)
#pragma unroll
    for (int n = 0; n < 8; ++n) acc[m][n] = (f32x4){0.f, 0.f, 0.f, 0.f};

  for (int k0 = 0; k0 < K; k0 += 32) {
    bf16x8 a[2], b[8];
#pragma unroll
    for (int m = 0; m < 2; ++m) {
      int rr = rbase + m * 16 + r16;
      if (rr >= M) rr = M - 1;
      a[m] = *(const bf16x8*)(A + (size_t)rr * K + k0 + kg);
    }
#pragma unroll
    for (int n = 0; n < 8; ++n) {
      b[n] = *(const bf16x8*)(W + (size_t)(colt + n * 16 + r16) * K + k0 + kg);
    }
#pragma unroll
    for (int m = 0; m < 2; ++m)
#pragma unroll
      for (int n = 0; n < 8; ++n)
        acc[m][n] = __builtin_amdgcn_mfma_f32_16x16x32_bf16(a[m], b[n], acc[m][n], 0, 0, 0);
  }

  int rowoff = (lane >> 4) * 4;
#pragma unroll
  for (int m = 0; m < 2; ++m) {
#pragma unroll
    for (int j = 0; j < 4; ++j) {
      int row = rbase + m * 16 + rowoff + j;
      if (row >= M) continue;
#pragma unroll
      for (int n = 0; n < 8; ++n) {
        int col = colt + n * 16 + r16;
        float v = acc[m][n][j] + bias[col];
        if (relu) v = fmaxf(v, 0.f);
        C[(size_t)row * NC + col] = f2bf(v);
      }
    }
  }
}

// ---------------- aggregation: h2[n] = 2*linx[n] + sum_{e->n} linx[src] -----
// bf16 in/out, 1 wave per node, lane handles cols {2*lane, 2*lane+1}
__global__ __launch_bounds__(256) void aggregate2(const uint* __restrict__ lx,
                                                  const int* __restrict__ rp,
                                                  const int* __restrict__ elist,
                                                  uint* __restrict__ h2) {
  int wv = threadIdx.x >> 6, lane = threadIdx.x & 63;
  int n = blockIdx.x * 4 + wv;
  int beg = rp[n], end = rp[n + 1];
  uint u = lx[(size_t)n * 64 + lane];
  float a0 = 2.f * bflo(u), a1 = 2.f * bfhi(u);
  int e = beg;
  for (; e + 4 <= end; e += 4) {
    int s0 = elist[e], s1 = elist[e + 1], s2 = elist[e + 2], s3 = elist[e + 3];
    uint u0 = lx[(size_t)s0 * 64 + lane];
    uint u1 = lx[(size_t)s1 * 64 + lane];
    uint u2 = lx[(size_t)s2 * 64 + lane];
    uint u3 = lx[(size_t)s3 * 64 + lane];
    a0 += bflo(u0) + bflo(u1) + bflo(u2) + bflo(u3);
    a1 += bfhi(u0) + bfhi(u1) + bfhi(u2) + bfhi(u3);
  }
  for (; e < end; ++e) {
    uint u0 = lx[(size_t)elist[e] * 64 + lane];
    a0 += bflo(u0);
    a1 += bfhi(u0);
  }
  h2[(size_t)n * 64 + lane] = (uint)f2bf(a0) | ((uint)f2bf(a1) << 16);
}

// ---------------- global mean pool (batch sorted), bf16 input ---------------
__global__ __launch_bounds__(128) void pool2(const uint* __restrict__ h,
                                             const int* __restrict__ batch,
                                             float* __restrict__ g) {
  int gg = blockIdx.x;   // graph id
  int j = threadIdx.x;   // 0..127 -> cols 2j, 2j+1
  int lo = 0, hi = N_NODESC;
  while (lo < hi) { int mid = (lo + hi) >> 1; if (batch[mid] < gg) lo = mid + 1; else hi = mid; }
  int beg = lo;
  hi = N_NODESC;
  while (lo < hi) { int mid = (lo + hi) >> 1; if (batch[mid] < gg + 1) lo = mid + 1; else hi = mid; }
  int end = lo;
  float a0 = 0.f, a1 = 0.f;
  for (int n = beg; n < end; ++n) {
    uint u = h[(size_t)n * 128 + j];
    a0 += bflo(u);
    a1 += bfhi(u);
  }
  float c = fmaxf((float)(end - beg), 1.0f);
  g[(size_t)gg * 256 + 2 * j] = a0 / c;
  g[(size_t)gg * 256 + 2 * j + 1] = a1 / c;
}

// ---------------- per-property heads (8 graphs per block) -------------------
__global__ __launch_bounds__(128) void head_kernel(const float* __restrict__ g,
    const float* __restrict__ w1, const float* __restrict__ b1,
    const float* __restrict__ w2, const float* __restrict__ b2,
    float* __restrict__ out) {
  int p = blockIdx.y;
  int g0 = blockIdx.x * 8;
  int t = threadIdx.x;  // 0..127  (= hidden unit h')
  __shared__ float gs[8][256];
  for (int i = t; i < 8 * 256; i += 128)
    gs[i >> 8][i & 255] = g[(size_t)(g0 + (i >> 8)) * 256 + (i & 255)];
  __syncthreads();
  const float4* w4 = (const float4*)(w1 + ((size_t)p * 128 + t) * 256);
  float bv = b1[p * 128 + t];
  float acc[8];
#pragma unroll
  for (int q = 0; q < 8; ++q) acc[q] = bv;
  for (int d4 = 0; d4 < 64; ++d4) {
    float4 wv = w4[d4];
#pragma unroll
    for (int q = 0; q < 8; ++q) {
      acc[q] += gs[q][d4 * 4 + 0] * wv.x + gs[q][d4 * 4 + 1] * wv.y +
                gs[q][d4 * 4 + 2] * wv.z + gs[q][d4 * 4 + 3] * wv.w;
    }
  }
  float w2v = w2[p * 128 + t];
  __shared__ float red[2][8];
  int wave = t >> 6, lane = t & 63;
#pragma unroll
  for (int q = 0; q < 8; ++q) {
    float v = fmaxf(acc[q], 0.f) * w2v;
    for (int o = 32; o > 0; o >>= 1) v += __shfl_down(v, o, 64);
    if (lane == 0) red[wave][q] = v;
  }
  __syncthreads();
  if (t < 8) out[(size_t)(g0 + t) * 8 + p] = red[0][t] + red[1][t] + b2[p];
}

extern "C" void kernel_launch(void* const* d_in, const int* in_sizes, int n_in,
                              void* d_out, int out_size, void* d_ws, size_t ws_size,
                              hipStream_t stream) {
  const int*   x     = (const int*)d_in[0];
  const int*   ei    = (const int*)d_in[1];
  const int*   batch = (const int*)d_in[2];
  const float* emb24 = (const float*)d_in[3];
  const float* emb72 = (const float*)d_in[4];
  const float* lin1w = (const float*)d_in[5];
  const float* lin1b = (const float*)d_in[6];
  const float* qa1w  = (const float*)d_in[7];
  const float* qa1b  = (const float*)d_in[8];
  const float* lin2w = (const float*)d_in[9];
  const float* lin2b = (const float*)d_in[10];
  const float* qa2w  = (const float*)d_in[11];
  const float* qa2b  = (const float*)d_in[12];
  const float* hw1   = (const float*)d_in[13];
  const float* hb1   = (const float*)d_in[14];
  const float* hw2   = (const float*)d_in[15];
  const float* hb2   = (const float*)d_in[16];
  float* out = (float*)d_out;

  const int* srcv = ei;
  const int* dstv = ei + N_EDGESC;

  char* wsb = (char*)d_ws;
  size_t off = 0;
  auto alloc = [&](size_t b) { char* p = wsb + off; off += (b + 255) & ~(size_t)255; return p; };
  ushort* feat  = (ushort*)alloc((size_t)N_NODESC * 96 * 2);
  ushort* linx  = (ushort*)alloc((size_t)N_NODESC * 128 * 2);
  ushort* h2    = (ushort*)alloc((size_t)N_NODESC * 128 * 2);
  ushort* h     = (ushort*)alloc((size_t)N_NODESC * 256 * 2);
  float*  gbuf  = (float*)alloc((size_t)NGC * 256 * 4);
  ushort* qe1   = (ushort*)alloc(256 * 128 * 2);
  ushort* qe2   = (ushort*)alloc(256 * 128 * 2);
  ushort* l1w   = (ushort*)alloc(128 * 96 * 2);
  ushort* l2w   = (ushort*)alloc(128 * 256 * 2);
  int*    rp    = (int*)alloc((size_t)(N_NODESC + 1) * 4);
  int*    cnt   = (int*)alloc((size_t)N_NODESC * 4);
  int*    elist = (int*)alloc((size_t)N_EDGESC * 4);

  // weight prep + features
  prep_qaeff<<<256, 128, 0, stream>>>(qa1w, qe1);
  prep_qaeff<<<256, 128, 0, stream>>>(qa2w, qe2);
  prep_lin1<<<128, 128, 0, stream>>>(lin1w, l1w);
  prep_lin2<<<128, 256, 0, stream>>>(lin2w, l2w);
  feat_kernel<<<N_NODESC, 128, 0, stream>>>(x, emb24, emb72, feat);

  // CSR build (reused by both layers)
  hipMemsetAsync(cnt, 0, (size_t)N_NODESC * 4, stream);
  count_kernel<<<(N_EDGESC + 255) / 256, 256, 0, stream>>>(dstv, cnt, N_EDGESC);
  scan_kernel<<<1, 1024, 0, stream>>>(cnt, rp, N_NODESC);
  hipMemsetAsync(cnt, 0, (size_t)N_NODESC * 4, stream);
  fill_kernel<<<(N_EDGESC + 255) / 256, 256, 0, stream>>>(srcv, dstv, rp, cnt, elist, N_EDGESC);

  int gm = (N_NODESC + 127) / 128;

  // layer 1
  mfma_gemm<<<dim3(gm, 1), 256, 0, stream>>>(feat, l1w, lin1b, linx, N_NODESC, 96, 128, 0);
  aggregate2<<<N_NODESC / 4, 256, 0, stream>>>((const uint*)linx, rp, elist, (uint*)h2);
  mfma_gemm<<<dim3(gm, 2), 256, 0, stream>>>(h2, qe1, qa1b, h, N_NODESC, 128, 256, 1);

  // layer 2
  mfma_gemm<<<dim3(gm, 1), 256, 0, stream>>>(h, l2w, lin2b, linx, N_NODESC, 256, 128, 0);
  aggregate2<<<N_NODESC / 4, 256, 0, stream>>>((const uint*)linx, rp, elist, (uint*)h2);
  mfma_gemm<<<dim3(gm, 2), 256, 0, stream>>>(h2, qe2, qa2b, h, N_NODESC, 128, 256, 1);

  // pool + heads
  pool2<<<NGC, 128, 0, stream>>>((const uint*)h, batch, gbuf);
  head_kernel<<<dim3(NGC / 8, NPC), 128, 0, stream>>>(gbuf, hw1, hb1, hw2, hb2, out);
}

// Round 3
// 327.462 us; speedup vs baseline: 2.4667x; 1.6814x over previous
//
#include <hip/hip_runtime.h>
#include <hip/hip_bf16.h>

#define N_NODESC 50000
#define N_EDGESC 1600000
#define NGC 1024
#define NPC 8
#define NBIN 196          // dst>>8 buckets (256 nodes each)
#define NBLKE 391         // edge chunks of 4096

typedef __attribute__((ext_vector_type(8))) short bf16x8;
typedef __attribute__((ext_vector_type(4))) float f32x4;

__device__ inline ushort f2bf(float f) {
  union { float f; uint u; } v; v.f = f;
  uint u = v.u;
  u += 0x7FFF + ((u >> 16) & 1);
  return (ushort)(u >> 16);
}
__device__ inline float bflo(uint u) {
  union { uint u; float f; } v; v.u = u << 16; return v.f;
}
__device__ inline float bfhi(uint u) {
  union { uint u; float f; } v; v.u = u & 0xFFFF0000u; return v.f;
}

// ---------------- weight prep ----------------
__global__ void prep_qaeff(const float* __restrict__ qaw, ushort* __restrict__ eff) {
  int k = blockIdx.x;
  int j = threadIdx.x;
  const float* r = qaw + (size_t)k * 256;
  float v;
  if (j < 64) {
    v = r[j] + r[128 + j] + r[192 + j];
  } else {
    int j2 = j - 64;
    v = r[64 + j2] + r[128 + j2] + 2.0f * r[192 + j2];
  }
  eff[(size_t)k * 128 + j] = f2bf(v);
}

__global__ void prep_lin1(const float* __restrict__ w, ushort* __restrict__ o) {
  int r = blockIdx.x;
  int t = threadIdx.x;
  if (t < 96) o[(size_t)r * 96 + t] = (t < 68) ? f2bf(w[(size_t)r * 68 + t]) : (ushort)0;
}

__global__ void prep_lin2(const float* __restrict__ w, ushort* __restrict__ o) {
  int r = blockIdx.x;
  int t = threadIdx.x;
  o[(size_t)r * 256 + t] = f2bf(w[(size_t)r * 256 + t]);
}

__global__ void feat_kernel(const int* __restrict__ x, const float* __restrict__ e24,
                            const float* __restrict__ e72, ushort* __restrict__ feat) {
  int n = blockIdx.x;
  int t = threadIdx.x;
  if (t >= 96) return;
  float v = 0.f;
  if (t < 4) v = (float)x[n * 4 + t];
  else if (t < 36) { int kk = t - 4;  int f = kk >> 3, c = kk & 7; v = e24[(x[n * 4 + f] % 24) * 8 + c]; }
  else if (t < 68) { int kk = t - 36; int f = kk >> 3, c = kk & 7; v = e72[(x[n * 4 + f] % 72) * 8 + c]; }
  feat[(size_t)n * 96 + t] = f2bf(v);
}

// ---------------- CSR build: bucketed two-pass sort ----------------
// A1: per-chunk histogram over 196 buckets
__global__ __launch_bounds__(256) void csr_hist(const int* __restrict__ dst,
                                                int* __restrict__ bh, int E) {
  __shared__ int hist[NBIN];
  int t = threadIdx.x, blk = blockIdx.x;
  if (t < NBIN) hist[t] = 0;
  __syncthreads();
  int base = blk * 4096;
#pragma unroll
  for (int i = 0; i < 16; ++i) {
    int idx = base + i * 256 + t;
    if (idx < E) atomicAdd(&hist[dst[idx] >> 8], 1);
  }
  __syncthreads();
  if (t < NBIN) bh[(size_t)t * NBLKE + blk] = hist[t];
}

// S1: per-bin exclusive prefix over chunks (one wave per bin) + bin totals
__global__ __launch_bounds__(64) void csr_scan_bins(int* __restrict__ bh, int* __restrict__ bt) {
  int bin = blockIdx.x;
  int lane = threadIdx.x;
  int carry = 0;
  int* row = bh + (size_t)bin * NBLKE;
  for (int c = 0; c < NBLKE; c += 64) {
    int j = c + lane;
    int v = (j < NBLKE) ? row[j] : 0;
    int incl = v;
#pragma unroll
    for (int off = 1; off < 64; off <<= 1) {
      int u = __shfl_up(incl, off, 64);
      if (lane >= off) incl += u;
    }
    if (j < NBLKE) row[j] = carry + incl - v;
    carry += __shfl(incl, 63, 64);
  }
  if (lane == 0) bt[bin] = carry;
}

// S2: exclusive scan of bin totals -> bucket bases (bb[NBIN]=E)
__global__ __launch_bounds__(256) void csr_scan_bases(const int* __restrict__ bt,
                                                      int* __restrict__ bb) {
  __shared__ int s[256];
  int t = threadIdx.x;
  int v = (t < NBIN) ? bt[t] : 0;
  s[t] = v;
  __syncthreads();
  for (int off = 1; off < 256; off <<= 1) {
    int u = (t >= off) ? s[t - off] : 0;
    __syncthreads();
    s[t] += u;
    __syncthreads();
  }
  if (t < NBIN) bb[t] = s[t] - v;
  if (t == NBIN - 1) bb[NBIN] = s[t];
}

// A3: scatter packed edges into bucket-grouped tmp
__global__ __launch_bounds__(256) void csr_scatter(const int* __restrict__ src,
                                                   const int* __restrict__ dst,
                                                   const int* __restrict__ bh,
                                                   const int* __restrict__ bb,
                                                   uint* __restrict__ tmp, int E) {
  __shared__ int cur[NBIN];
  int t = threadIdx.x, blk = blockIdx.x;
  if (t < NBIN) cur[t] = bb[t] + bh[(size_t)t * NBLKE + blk];
  __syncthreads();
  int base = blk * 4096;
#pragma unroll
  for (int i = 0; i < 16; ++i) {
    int idx = base + i * 256 + t;
    if (idx < E) {
      int d = dst[idx];
      uint p = ((uint)d << 16) | (uint)src[idx];
      int pos = atomicAdd(&cur[d >> 8], 1);
      tmp[pos] = p;
    }
  }
}

// B: per-bucket counting sort by node -> elist (ushort src) + rp
__global__ __launch_bounds__(256) void csr_bucket_sort(const uint* __restrict__ tmp,
                                                       const int* __restrict__ bb,
                                                       ushort* __restrict__ elist,
                                                       int* __restrict__ rp) {
  __shared__ int cnt[256];
  __shared__ int sc[256];
  int b = blockIdx.x, t = threadIdx.x;
  int base = bb[b], end = bb[b + 1];
  cnt[t] = 0;
  __syncthreads();
  for (int i = base + t; i < end; i += 256)
    atomicAdd(&cnt[(tmp[i] >> 16) & 255], 1);
  __syncthreads();
  int v = cnt[t];
  sc[t] = v;
  __syncthreads();
  for (int off = 1; off < 256; off <<= 1) {
    int u = (t >= off) ? sc[t - off] : 0;
    __syncthreads();
    sc[t] += u;
    __syncthreads();
  }
  int excl = sc[t] - v;
  int node = (b << 8) + t;
  if (node < N_NODESC) rp[node] = base + excl;
  if (b == NBIN - 1 && t == 0) rp[N_NODESC] = bb[NBIN];
  cnt[t] = base + excl;  // reuse as global cursor
  __syncthreads();
  for (int i = base + t; i < end; i += 256) {
    uint p = tmp[i];
    int pos = atomicAdd(&cnt[(p >> 16) & 255], 1);
    elist[pos] = (ushort)(p & 0xFFFFu);
  }
}

// ---------------- MFMA GEMM: C[M,NC] = act(A[M,K] @ W[NC,K]^T + b) ----------
__global__ __launch_bounds__(256) void mfma_gemm(
    const ushort* __restrict__ A, const ushort* __restrict__ W,
    const float* __restrict__ bias, ushort* __restrict__ C,
    int M, int K, int NC, int relu) {
  int lane = threadIdx.x & 63;
  int wv = threadIdx.x >> 6;
  int rbase = blockIdx.x * 128 + wv * 32;
  int colt = blockIdx.y * 128;
  int r16 = lane & 15;
  int kg = (lane >> 4) * 8;

  f32x4 acc[2][8];
#pragma unroll
  for (int m = 0; m < 2; ++m)
#pragma unroll
    for (int n = 0; n < 8; ++n) acc[m][n] = (f32x4){0.f, 0.f, 0.f, 0.f};

  for (int k0 = 0; k0 < K; k0 += 32) {
    bf16x8 a[2], b[8];
#pragma unroll
    for (int m = 0; m < 2; ++m) {
      int rr = rbase + m * 16 + r16;
      if (rr >= M) rr = M - 1;
      a[m] = *(const bf16x8*)(A + (size_t)rr * K + k0 + kg);
    }
#pragma unroll
    for (int n = 0; n < 8; ++n) {
      b[n] = *(const bf16x8*)(W + (size_t)(colt + n * 16 + r16) * K + k0 + kg);
    }
#pragma unroll
    for (int m = 0; m < 2; ++m)
#pragma unroll
      for (int n = 0; n < 8; ++n)
        acc[m][n] = __builtin_amdgcn_mfma_f32_16x16x32_bf16(a[m], b[n], acc[m][n], 0, 0, 0);
  }

  int rowoff = (lane >> 4) * 4;
#pragma unroll
  for (int m = 0; m < 2; ++m) {
#pragma unroll
    for (int j = 0; j < 4; ++j) {
      int row = rbase + m * 16 + rowoff + j;
      if (row >= M) continue;
#pragma unroll
      for (int n = 0; n < 8; ++n) {
        int col = colt + n * 16 + r16;
        float v = acc[m][n][j] + bias[col];
        if (relu) v = fmaxf(v, 0.f);
        C[(size_t)row * NC + col] = f2bf(v);
      }
    }
  }
}

// ---------------- aggregation: h2[n] = 2*linx[n] + sum_{e->n} linx[src] -----
__global__ __launch_bounds__(256) void aggregate2(const uint* __restrict__ lx,
                                                  const int* __restrict__ rp,
                                                  const ushort* __restrict__ elist,
                                                  uint* __restrict__ h2) {
  int wv = threadIdx.x >> 6, lane = threadIdx.x & 63;
  int n = blockIdx.x * 4 + wv;
  int beg = rp[n], end = rp[n + 1];
  uint u = lx[(size_t)n * 64 + lane];
  float a0 = 2.f * bflo(u), a1 = 2.f * bfhi(u);
  int e = beg;
  for (; e + 8 <= end; e += 8) {
    int s0 = elist[e], s1 = elist[e + 1], s2 = elist[e + 2], s3 = elist[e + 3];
    int s4 = elist[e + 4], s5 = elist[e + 5], s6 = elist[e + 6], s7 = elist[e + 7];
    uint u0 = lx[(size_t)s0 * 64 + lane];
    uint u1 = lx[(size_t)s1 * 64 + lane];
    uint u2 = lx[(size_t)s2 * 64 + lane];
    uint u3 = lx[(size_t)s3 * 64 + lane];
    uint u4 = lx[(size_t)s4 * 64 + lane];
    uint u5 = lx[(size_t)s5 * 64 + lane];
    uint u6 = lx[(size_t)s6 * 64 + lane];
    uint u7 = lx[(size_t)s7 * 64 + lane];
    a0 += bflo(u0) + bflo(u1) + bflo(u2) + bflo(u3);
    a1 += bfhi(u0) + bfhi(u1) + bfhi(u2) + bfhi(u3);
    a0 += bflo(u4) + bflo(u5) + bflo(u6) + bflo(u7);
    a1 += bfhi(u4) + bfhi(u5) + bfhi(u6) + bfhi(u7);
  }
  for (; e < end; ++e) {
    uint u0 = lx[(size_t)elist[e] * 64 + lane];
    a0 += bflo(u0);
    a1 += bfhi(u0);
  }
  h2[(size_t)n * 64 + lane] = (uint)f2bf(a0) | ((uint)f2bf(a1) << 16);
}

// ---------------- global mean pool (batch sorted), bf16 input ---------------
__global__ __launch_bounds__(128) void pool2(const uint* __restrict__ h,
                                             const int* __restrict__ batch,
                                             float* __restrict__ g) {
  int gg = blockIdx.x;
  int j = threadIdx.x;
  int lo = 0, hi = N_NODESC;
  while (lo < hi) { int mid = (lo + hi) >> 1; if (batch[mid] < gg) lo = mid + 1; else hi = mid; }
  int beg = lo;
  hi = N_NODESC;
  while (lo < hi) { int mid = (lo + hi) >> 1; if (batch[mid] < gg + 1) lo = mid + 1; else hi = mid; }
  int end = lo;
  float a0 = 0.f, a1 = 0.f;
  for (int n = beg; n < end; ++n) {
    uint u = h[(size_t)n * 128 + j];
    a0 += bflo(u);
    a1 += bfhi(u);
  }
  float c = fmaxf((float)(end - beg), 1.0f);
  g[(size_t)gg * 256 + 2 * j] = a0 / c;
  g[(size_t)gg * 256 + 2 * j + 1] = a1 / c;
}

// ---------------- per-property heads (8 graphs per block) -------------------
__global__ __launch_bounds__(128) void head_kernel(const float* __restrict__ g,
    const float* __restrict__ w1, const float* __restrict__ b1,
    const float* __restrict__ w2, const float* __restrict__ b2,
    float* __restrict__ out) {
  int p = blockIdx.y;
  int g0 = blockIdx.x * 8;
  int t = threadIdx.x;
  __shared__ float gs[8][256];
  for (int i = t; i < 8 * 256; i += 128)
    gs[i >> 8][i & 255] = g[(size_t)(g0 + (i >> 8)) * 256 + (i & 255)];
  __syncthreads();
  const float4* w4 = (const float4*)(w1 + ((size_t)p * 128 + t) * 256);
  float bv = b1[p * 128 + t];
  float acc[8];
#pragma unroll
  for (int q = 0; q < 8; ++q) acc[q] = bv;
  for (int d4 = 0; d4 < 64; ++d4) {
    float4 wv = w4[d4];
#pragma unroll
    for (int q = 0; q < 8; ++q) {
      acc[q] += gs[q][d4 * 4 + 0] * wv.x + gs[q][d4 * 4 + 1] * wv.y +
                gs[q][d4 * 4 + 2] * wv.z + gs[q][d4 * 4 + 3] * wv.w;
    }
  }
  float w2v = w2[p * 128 + t];
  __shared__ float red[2][8];
  int wave = t >> 6, lane = t & 63;
#pragma unroll
  for (int q = 0; q < 8; ++q) {
    float v = fmaxf(acc[q], 0.f) * w2v;
    for (int o = 32; o > 0; o >>= 1) v += __shfl_down(v, o, 64);
    if (lane == 0) red[wave][q] = v;
  }
  __syncthreads();
  if (t < 8) out[(size_t)(g0 + t) * 8 + p] = red[0][t] + red[1][t] + b2[p];
}

extern "C" void kernel_launch(void* const* d_in, const int* in_sizes, int n_in,
                              void* d_out, int out_size, void* d_ws, size_t ws_size,
                              hipStream_t stream) {
  const int*   x     = (const int*)d_in[0];
  const int*   ei    = (const int*)d_in[1];
  const int*   batch = (const int*)d_in[2];
  const float* emb24 = (const float*)d_in[3];
  const float* emb72 = (const float*)d_in[4];
  const float* lin1w = (const float*)d_in[5];
  const float* lin1b = (const float*)d_in[6];
  const float* qa1w  = (const float*)d_in[7];
  const float* qa1b  = (const float*)d_in[8];
  const float* lin2w = (const float*)d_in[9];
  const float* lin2b = (const float*)d_in[10];
  const float* qa2w  = (const float*)d_in[11];
  const float* qa2b  = (const float*)d_in[12];
  const float* hw1   = (const float*)d_in[13];
  const float* hb1   = (const float*)d_in[14];
  const float* hw2   = (const float*)d_in[15];
  const float* hb2   = (const float*)d_in[16];
  float* out = (float*)d_out;

  const int* srcv = ei;
  const int* dstv = ei + N_EDGESC;

  char* wsb = (char*)d_ws;
  size_t off = 0;
  auto alloc = [&](size_t b) { char* p = wsb + off; off += (b + 255) & ~(size_t)255; return p; };
  ushort* feat  = (ushort*)alloc((size_t)N_NODESC * 96 * 2);
  ushort* linx  = (ushort*)alloc((size_t)N_NODESC * 128 * 2);
  ushort* h2    = (ushort*)alloc((size_t)N_NODESC * 128 * 2);
  ushort* h     = (ushort*)alloc((size_t)N_NODESC * 256 * 2);
  float*  gbuf  = (float*)alloc((size_t)NGC * 256 * 4);
  ushort* qe1   = (ushort*)alloc(256 * 128 * 2);
  ushort* qe2   = (ushort*)alloc(256 * 128 * 2);
  ushort* l1w   = (ushort*)alloc(128 * 96 * 2);
  ushort* l2w   = (ushort*)alloc(128 * 256 * 2);
  int*    rp    = (int*)alloc((size_t)(N_NODESC + 1) * 4);
  ushort* elist = (ushort*)alloc((size_t)N_EDGESC * 2);
  int*    bh    = (int*)alloc((size_t)NBIN * NBLKE * 4);
  int*    bt    = (int*)alloc((size_t)NBIN * 4);
  int*    bb    = (int*)alloc((size_t)(NBIN + 1) * 4);
  uint*   tmp   = (uint*)h;  // alias: h unused until after aggregation

  // weight prep + features
  prep_qaeff<<<256, 128, 0, stream>>>(qa1w, qe1);
  prep_qaeff<<<256, 128, 0, stream>>>(qa2w, qe2);
  prep_lin1<<<128, 128, 0, stream>>>(lin1w, l1w);
  prep_lin2<<<128, 256, 0, stream>>>(lin2w, l2w);
  feat_kernel<<<N_NODESC, 128, 0, stream>>>(x, emb24, emb72, feat);

  // CSR build: bucketed two-pass sort
  csr_hist<<<NBLKE, 256, 0, stream>>>(dstv, bh, N_EDGESC);
  csr_scan_bins<<<NBIN, 64, 0, stream>>>(bh, bt);
  csr_scan_bases<<<1, 256, 0, stream>>>(bt, bb);
  csr_scatter<<<NBLKE, 256, 0, stream>>>(srcv, dstv, bh, bb, tmp, N_EDGESC);
  csr_bucket_sort<<<NBIN, 256, 0, stream>>>(tmp, bb, elist, rp);

  int gm = (N_NODESC + 127) / 128;

  // layer 1
  mfma_gemm<<<dim3(gm, 1), 256, 0, stream>>>(feat, l1w, lin1b, linx, N_NODESC, 96, 128, 0);
  aggregate2<<<N_NODESC / 4, 256, 0, stream>>>((const uint*)linx, rp, elist, (uint*)h2);
  mfma_gemm<<<dim3(gm, 2), 256, 0, stream>>>(h2, qe1, qa1b, h, N_NODESC, 128, 256, 1);

  // layer 2
  mfma_gemm<<<dim3(gm, 1), 256, 0, stream>>>(h, l2w, lin2b, linx, N_NODESC, 256, 128, 0);
  aggregate2<<<N_NODESC / 4, 256, 0, stream>>>((const uint*)linx, rp, elist, (uint*)h2);
  mfma_gemm<<<dim3(gm, 2), 256, 0, stream>>>(h2, qe2, qa2b, h, N_NODESC, 128, 256, 1);

  // pool + heads
  pool2<<<NGC, 128, 0, stream>>>((const uint*)h, batch, gbuf);
  head_kernel<<<dim3(NGC / 8, NPC), 128, 0, stream>>>(gbuf, hw1, hb1, hw2, hb2, out);
}